// Round 1
// baseline (357.575 us; speedup 1.0000x reference)
//
#include <hip/hip_runtime.h>
#include <math.h>

// Problem constants (fixed by the reference setup_inputs).
#define BB 16
#define LL 4096
#define WW 1024
#define NQ 4
// scale = W^-0.5 = 1/32
#define SCALE 0.03125f

// ---------------------------------------------------------------------------
// Kernel 1: fused scores + online softmax + weighted accumulation.
// grid = BB * P blocks, 256 threads (4 waves). Each wave owns LL/(4P)
// contiguous rows of L. Masked rows are skipped entirely (no h load).
// Each block writes one partial (m, s, o[NQ][WW]) per q to workspace.
// ---------------------------------------------------------------------------
__global__ __launch_bounds__(256, 2) void pool_main(
    const float* __restrict__ h,      // (B, L, W)
    const int* __restrict__ mask,     // (B, L), nonzero = masked out
    const float* __restrict__ queries,// (Q, W)
    float* __restrict__ Opart,        // (B, P, NQ, WW)
    float* __restrict__ MSpart,       // (B, P, NQ, 2)  [m, s]
    int P)
{
    const int tid  = threadIdx.x;
    const int lane = tid & 63;
    const int wv   = tid >> 6;
    const int b    = blockIdx.x / P;
    const int p    = blockIdx.x % P;
    const int rpw  = LL / (P * 4);           // rows per wave
    const int l0   = (p * 4 + wv) * rpw;     // this wave's first row

    // Load queries once, pre-scaled by 1/32. Lane's 16 w-positions:
    // w = j*256 + lane*4 + k, j in [0,4), k in [0,4).
    float4 qreg[NQ][4];
#pragma unroll
    for (int q = 0; q < NQ; ++q) {
#pragma unroll
        for (int j = 0; j < 4; ++j) {
            float4 v = *reinterpret_cast<const float4*>(
                queries + q * WW + j * 256 + lane * 4);
            qreg[q][j].x = v.x * SCALE;
            qreg[q][j].y = v.y * SCALE;
            qreg[q][j].z = v.z * SCALE;
            qreg[q][j].w = v.w * SCALE;
        }
    }

    float4 o[NQ][4];
    float  m[NQ], s[NQ];
#pragma unroll
    for (int q = 0; q < NQ; ++q) {
        m[q] = -INFINITY;
        s[q] = 0.0f;
#pragma unroll
        for (int j = 0; j < 4; ++j)
            o[q][j] = make_float4(0.f, 0.f, 0.f, 0.f);
    }

    for (int g = 0; g < rpw; g += 64) {
        const int nrows = (rpw - g < 64) ? (rpw - g) : 64;
        int mv = 0;
        if (lane < nrows) mv = mask[(size_t)b * LL + l0 + g + lane];
        const unsigned long long mb = __ballot(mv != 0);

        for (int r = 0; r < nrows; ++r) {
            if ((mb >> r) & 1ull) continue;   // masked row: contributes 0
            const float* hrow = h + ((size_t)b * LL + (l0 + g + r)) * WW;
            float4 hv[4];
#pragma unroll
            for (int j = 0; j < 4; ++j)
                hv[j] = *reinterpret_cast<const float4*>(hrow + j * 256 + lane * 4);

            // per-lane partial dots
            float pd[NQ];
#pragma unroll
            for (int q = 0; q < NQ; ++q) {
                float acc = 0.f;
#pragma unroll
                for (int j = 0; j < 4; ++j) {
                    acc = fmaf(hv[j].x, qreg[q][j].x, acc);
                    acc = fmaf(hv[j].y, qreg[q][j].y, acc);
                    acc = fmaf(hv[j].z, qreg[q][j].z, acc);
                    acc = fmaf(hv[j].w, qreg[q][j].w, acc);
                }
                pd[q] = acc;
            }
            // butterfly reduce over 64 lanes (all lanes end with the total)
#pragma unroll
            for (int off = 32; off > 0; off >>= 1) {
#pragma unroll
                for (int q = 0; q < NQ; ++q)
                    pd[q] += __shfl_xor(pd[q], off);
            }

            // online softmax update (pd is wave-uniform -> uniform branches)
#pragma unroll
            for (int q = 0; q < NQ; ++q) {
                const float sc = pd[q];
                if (sc > m[q]) {
                    // rescale path: p = exp(0) = 1
                    const float c = __expf(m[q] - sc);   // exp(-inf)=0 on 1st row
                    s[q] = s[q] * c + 1.0f;
#pragma unroll
                    for (int j = 0; j < 4; ++j) {
                        o[q][j].x = o[q][j].x * c + hv[j].x;
                        o[q][j].y = o[q][j].y * c + hv[j].y;
                        o[q][j].z = o[q][j].z * c + hv[j].z;
                        o[q][j].w = o[q][j].w * c + hv[j].w;
                    }
                    m[q] = sc;
                } else {
                    const float pp = __expf(sc - m[q]);
                    s[q] += pp;
#pragma unroll
                    for (int j = 0; j < 4; ++j) {
                        o[q][j].x = fmaf(pp, hv[j].x, o[q][j].x);
                        o[q][j].y = fmaf(pp, hv[j].y, o[q][j].y);
                        o[q][j].z = fmaf(pp, hv[j].z, o[q][j].z);
                        o[q][j].w = fmaf(pp, hv[j].w, o[q][j].w);
                    }
                }
            }
        }
    }

    // ---------------- block-level merge of 4 wave partials -----------------
    __shared__ float lo[NQ][WW];      // 16 KB
    __shared__ float lm[4][NQ];
    __shared__ float lss[4][NQ];

    if (lane == 0) {
#pragma unroll
        for (int q = 0; q < NQ; ++q) { lm[wv][q] = m[q]; lss[wv][q] = s[q]; }
    }
    for (int i = tid; i < NQ * WW; i += 256) ((float*)lo)[i] = 0.f;
    __syncthreads();

    float M[NQ], fw[NQ];
#pragma unroll
    for (int q = 0; q < NQ; ++q) {
        M[q] = fmaxf(fmaxf(lm[0][q], lm[1][q]), fmaxf(lm[2][q], lm[3][q]));
        fw[q] = (m[q] == -INFINITY) ? 0.f : __expf(m[q] - M[q]);
    }

    // serialize waves into the shared accumulator (4 rounds)
    for (int t = 0; t < 4; ++t) {
        if (wv == t) {
#pragma unroll
            for (int q = 0; q < NQ; ++q) {
#pragma unroll
                for (int j = 0; j < 4; ++j) {
                    float* dst = &lo[q][j * 256 + lane * 4];
                    dst[0] += fw[q] * o[q][j].x;
                    dst[1] += fw[q] * o[q][j].y;
                    dst[2] += fw[q] * o[q][j].z;
                    dst[3] += fw[q] * o[q][j].w;
                }
            }
        }
        __syncthreads();
    }

    // combined s for the block
    float S[NQ];
#pragma unroll
    for (int q = 0; q < NQ; ++q) {
        float acc = 0.f;
#pragma unroll
        for (int t = 0; t < 4; ++t) {
            const float mt = lm[t][q];
            if (mt != -INFINITY) acc += __expf(mt - M[q]) * lss[t][q];
        }
        S[q] = acc;
    }

    float* Ob = Opart + ((size_t)(b * P + p) * NQ) * WW;
    for (int i = tid; i < NQ * WW; i += 256) Ob[i] = ((float*)lo)[i];
    if (tid < NQ) {
        const size_t base = ((size_t)(b * P + p) * NQ + tid) * 2;
        MSpart[base]     = M[tid];
        MSpart[base + 1] = S[tid];
    }
}

// ---------------------------------------------------------------------------
// Kernel 2: combine the P block-partials per (b, q) and write the output.
// grid = BB*NQ blocks, 256 threads; thread t owns w = 4t..4t+3.
// ---------------------------------------------------------------------------
__global__ __launch_bounds__(256) void pool_combine(
    const float* __restrict__ Opart,
    const float* __restrict__ MSpart,
    float* __restrict__ out,          // (B, Q*W)
    int P)
{
    const int b = blockIdx.x / NQ;
    const int q = blockIdx.x % NQ;
    const int tid = threadIdx.x;
    const int w = tid * 4;

    float M = -INFINITY;
    for (int i = 0; i < P; ++i)
        M = fmaxf(M, MSpart[((size_t)(b * P + i) * NQ + q) * 2]);

    float S = 0.f;
    float4 acc = make_float4(0.f, 0.f, 0.f, 0.f);
    for (int i = 0; i < P; ++i) {
        const size_t msb = ((size_t)(b * P + i) * NQ + q) * 2;
        const float mi = MSpart[msb];
        if (mi == -INFINITY) continue;
        const float f = __expf(mi - M);
        S += f * MSpart[msb + 1];
        const float4 v = *reinterpret_cast<const float4*>(
            Opart + ((size_t)(b * P + i) * NQ + q) * WW + w);
        acc.x = fmaf(f, v.x, acc.x);
        acc.y = fmaf(f, v.y, acc.y);
        acc.z = fmaf(f, v.z, acc.z);
        acc.w = fmaf(f, v.w, acc.w);
    }

    const float inv = 1.0f / S;
    float4 r;
    r.x = acc.x * inv; r.y = acc.y * inv; r.z = acc.z * inv; r.w = acc.w * inv;
    *reinterpret_cast<float4*>(out + (size_t)b * (NQ * WW) + q * WW + w) = r;
}

extern "C" void kernel_launch(void* const* d_in, const int* in_sizes, int n_in,
                              void* d_out, int out_size, void* d_ws, size_t ws_size,
                              hipStream_t stream) {
    const float* h       = (const float*)d_in[0];
    const int*   mask    = (const int*)d_in[1];
    const float* queries = (const float*)d_in[2];
    float*       out     = (float*)d_out;

    // pick the largest power-of-two P (blocks per b) the workspace allows
    int P = 32;
    while (P > 1) {
        size_t need = (size_t)BB * P * NQ * WW * sizeof(float)
                    + (size_t)BB * P * NQ * 2 * sizeof(float);
        if (need <= ws_size) break;
        P >>= 1;
    }

    float* Opart  = (float*)d_ws;
    float* MSpart = Opart + (size_t)BB * P * NQ * WW;

    pool_main<<<dim3(BB * P), dim3(256), 0, stream>>>(h, mask, queries,
                                                      Opart, MSpart, P);
    pool_combine<<<dim3(BB * NQ), dim3(256), 0, stream>>>(Opart, MSpart, out, P);
}

// Round 2
// 357.273 us; speedup vs baseline: 1.0008x; 1.0008x over previous
//
#include <hip/hip_runtime.h>
#include <math.h>

// Problem constants (fixed by the reference setup_inputs).
#define BB 16
#define LL 4096
#define WW 1024
#define NQ 4
// scale = W^-0.5 = 1/32
#define SCALE 0.03125f

// ---------------------------------------------------------------------------
// Kernel 1: fused scores + online softmax + weighted accumulation.
// grid = BB * P blocks, 256 threads (4 waves). Each wave owns LL/(4P)
// contiguous rows of L. Masked rows are skipped entirely (no h load).
// Unmasked rows are compacted via the ballot bitmap and processed in
// batches of 4 so that (a) 16 loads are in flight per iteration and
// (b) the 16 shfl-reduce chains interleave, hiding DS latency.
// Each block writes one partial (m, s, o[NQ][WW]) per q to workspace.
// ---------------------------------------------------------------------------
__global__ __launch_bounds__(256, 2) void pool_main(
    const float* __restrict__ h,      // (B, L, W)
    const int* __restrict__ mask,     // (B, L), nonzero = masked out
    const float* __restrict__ queries,// (Q, W)
    float* __restrict__ Opart,        // (B, P, NQ, WW)
    float* __restrict__ MSpart,       // (B, P, NQ, 2)  [m, s]
    int P)
{
    const int tid  = threadIdx.x;
    const int lane = tid & 63;
    const int wv   = tid >> 6;
    const int b    = blockIdx.x / P;
    const int p    = blockIdx.x % P;
    const int rpw  = LL / (P * 4);           // rows per wave
    const int l0   = (p * 4 + wv) * rpw;     // this wave's first row

    // Load queries once, pre-scaled by 1/32. Lane's 16 w-positions:
    // w = j*256 + lane*4 + k, j in [0,4), k in [0,4).
    float4 qreg[NQ][4];
#pragma unroll
    for (int q = 0; q < NQ; ++q) {
#pragma unroll
        for (int j = 0; j < 4; ++j) {
            float4 v = *reinterpret_cast<const float4*>(
                queries + q * WW + j * 256 + lane * 4);
            qreg[q][j].x = v.x * SCALE;
            qreg[q][j].y = v.y * SCALE;
            qreg[q][j].z = v.z * SCALE;
            qreg[q][j].w = v.w * SCALE;
        }
    }

    float4 o[NQ][4];
    float  m[NQ], s[NQ];
#pragma unroll
    for (int q = 0; q < NQ; ++q) {
        m[q] = -INFINITY;
        s[q] = 0.0f;
#pragma unroll
        for (int j = 0; j < 4; ++j)
            o[q][j] = make_float4(0.f, 0.f, 0.f, 0.f);
    }

    const float* hbase = h + (size_t)b * LL * WW;

    for (int g = 0; g < rpw; g += 64) {
        const int nrows = (rpw - g < 64) ? (rpw - g) : 64;
        int mv = 0;
        if (lane < nrows) mv = mask[(size_t)b * LL + l0 + g + lane];
        const unsigned long long mb = __ballot(mv != 0);
        unsigned long long valid = ~mb;
        if (nrows < 64) valid &= ((1ull << nrows) - 1ull);

        while (valid) {
            // ---- extract up to 4 unmasked rows (wave-uniform) ----
            int r[4];
            int vld[4];
#pragma unroll
            for (int k = 0; k < 4; ++k) {
                if (valid) {
                    r[k] = __ffsll((unsigned long long)valid) - 1;
                    valid &= valid - 1ull;
                    vld[k] = 1;
                } else {
                    r[k] = r[0];     // duplicate load, weight forced to 0
                    vld[k] = 0;
                }
            }

            // ---- issue all 16 loads (4 rows x 4 float4/lane) ----
            float4 hv[4][4];
#pragma unroll
            for (int k = 0; k < 4; ++k) {
                const float* hrow = hbase + (size_t)(l0 + g + r[k]) * WW;
#pragma unroll
                for (int j = 0; j < 4; ++j)
                    hv[k][j] = *reinterpret_cast<const float4*>(
                        hrow + j * 256 + lane * 4);
            }

            // ---- per-lane partial dots: 16 chains ----
            float pd[4][NQ];
#pragma unroll
            for (int k = 0; k < 4; ++k) {
#pragma unroll
                for (int q = 0; q < NQ; ++q) {
                    float acc = 0.f;
#pragma unroll
                    for (int j = 0; j < 4; ++j) {
                        acc = fmaf(hv[k][j].x, qreg[q][j].x, acc);
                        acc = fmaf(hv[k][j].y, qreg[q][j].y, acc);
                        acc = fmaf(hv[k][j].z, qreg[q][j].z, acc);
                        acc = fmaf(hv[k][j].w, qreg[q][j].w, acc);
                    }
                    pd[k][q] = acc;
                }
            }

            // ---- 16 interleaved butterfly reductions over 64 lanes ----
#pragma unroll
            for (int off = 32; off > 0; off >>= 1) {
#pragma unroll
                for (int k = 0; k < 4; ++k)
#pragma unroll
                    for (int q = 0; q < NQ; ++q)
                        pd[k][q] += __shfl_xor(pd[k][q], off);
            }

            // invalidate padded slots (-> p = 0)
#pragma unroll
            for (int k = 0; k < 4; ++k)
                if (!vld[k])
#pragma unroll
                    for (int q = 0; q < NQ; ++q) pd[k][q] = -INFINITY;

            // ---- batched online-softmax update (one rescale/batch) ----
#pragma unroll
            for (int q = 0; q < NQ; ++q) {
                const float bm = fmaxf(fmaxf(pd[0][q], pd[1][q]),
                                       fmaxf(pd[2][q], pd[3][q]));
                const float mn = fmaxf(m[q], bm);      // finite: >=1 valid row
                const float c  = __expf(m[q] - mn);    // exp(-inf)=0 first time
                float pr[4];
#pragma unroll
                for (int k = 0; k < 4; ++k)
                    pr[k] = __expf(pd[k][q] - mn);     // invalid -> 0
                s[q] = s[q] * c + ((pr[0] + pr[1]) + (pr[2] + pr[3]));
                m[q] = mn;
#pragma unroll
                for (int j = 0; j < 4; ++j) {
                    float x = o[q][j].x * c, y = o[q][j].y * c;
                    float z = o[q][j].z * c, w = o[q][j].w * c;
#pragma unroll
                    for (int k = 0; k < 4; ++k) {
                        x = fmaf(pr[k], hv[k][j].x, x);
                        y = fmaf(pr[k], hv[k][j].y, y);
                        z = fmaf(pr[k], hv[k][j].z, z);
                        w = fmaf(pr[k], hv[k][j].w, w);
                    }
                    o[q][j].x = x; o[q][j].y = y; o[q][j].z = z; o[q][j].w = w;
                }
            }
        }
    }

    // ---------------- block-level merge of 4 wave partials -----------------
    __shared__ float lo[NQ][WW];      // 16 KB
    __shared__ float lm[4][NQ];
    __shared__ float lss[4][NQ];

    if (lane == 0) {
#pragma unroll
        for (int q = 0; q < NQ; ++q) { lm[wv][q] = m[q]; lss[wv][q] = s[q]; }
    }
    for (int i = tid; i < NQ * WW; i += 256) ((float*)lo)[i] = 0.f;
    __syncthreads();

    float M[NQ], fw[NQ];
#pragma unroll
    for (int q = 0; q < NQ; ++q) {
        M[q] = fmaxf(fmaxf(lm[0][q], lm[1][q]), fmaxf(lm[2][q], lm[3][q]));
        fw[q] = (m[q] == -INFINITY) ? 0.f : __expf(m[q] - M[q]);
    }

    // serialize waves into the shared accumulator (4 rounds)
    for (int t = 0; t < 4; ++t) {
        if (wv == t) {
#pragma unroll
            for (int q = 0; q < NQ; ++q) {
#pragma unroll
                for (int j = 0; j < 4; ++j) {
                    float* dst = &lo[q][j * 256 + lane * 4];
                    dst[0] += fw[q] * o[q][j].x;
                    dst[1] += fw[q] * o[q][j].y;
                    dst[2] += fw[q] * o[q][j].z;
                    dst[3] += fw[q] * o[q][j].w;
                }
            }
        }
        __syncthreads();
    }

    // combined s for the block
    float S[NQ];
#pragma unroll
    for (int q = 0; q < NQ; ++q) {
        float acc = 0.f;
#pragma unroll
        for (int t = 0; t < 4; ++t) {
            const float mt = lm[t][q];
            if (mt != -INFINITY) acc += __expf(mt - M[q]) * lss[t][q];
        }
        S[q] = acc;
    }

    float* Ob = Opart + ((size_t)(b * P + p) * NQ) * WW;
    for (int i = tid; i < NQ * WW; i += 256) Ob[i] = ((float*)lo)[i];
    if (tid < NQ) {
        const size_t base = ((size_t)(b * P + p) * NQ + tid) * 2;
        MSpart[base]     = M[tid];
        MSpart[base + 1] = S[tid];
    }
}

// ---------------------------------------------------------------------------
// Kernel 2: combine the P block-partials per (b, q) and write the output.
// grid = BB*NQ blocks, 256 threads; thread t owns w = 4t..4t+3.
// ---------------------------------------------------------------------------
__global__ __launch_bounds__(256) void pool_combine(
    const float* __restrict__ Opart,
    const float* __restrict__ MSpart,
    float* __restrict__ out,          // (B, Q*W)
    int P)
{
    const int b = blockIdx.x / NQ;
    const int q = blockIdx.x % NQ;
    const int tid = threadIdx.x;
    const int w = tid * 4;

    float M = -INFINITY;
    for (int i = 0; i < P; ++i)
        M = fmaxf(M, MSpart[((size_t)(b * P + i) * NQ + q) * 2]);

    float S = 0.f;
    float4 acc = make_float4(0.f, 0.f, 0.f, 0.f);
    for (int i = 0; i < P; ++i) {
        const size_t msb = ((size_t)(b * P + i) * NQ + q) * 2;
        const float mi = MSpart[msb];
        if (mi == -INFINITY) continue;
        const float f = __expf(mi - M);
        S += f * MSpart[msb + 1];
        const float4 v = *reinterpret_cast<const float4*>(
            Opart + ((size_t)(b * P + i) * NQ + q) * WW + w);
        acc.x = fmaf(f, v.x, acc.x);
        acc.y = fmaf(f, v.y, acc.y);
        acc.z = fmaf(f, v.z, acc.z);
        acc.w = fmaf(f, v.w, acc.w);
    }

    const float inv = 1.0f / S;
    float4 r;
    r.x = acc.x * inv; r.y = acc.y * inv; r.z = acc.z * inv; r.w = acc.w * inv;
    *reinterpret_cast<float4*>(out + (size_t)b * (NQ * WW) + q * WW + w) = r;
}

extern "C" void kernel_launch(void* const* d_in, const int* in_sizes, int n_in,
                              void* d_out, int out_size, void* d_ws, size_t ws_size,
                              hipStream_t stream) {
    const float* h       = (const float*)d_in[0];
    const int*   mask    = (const int*)d_in[1];
    const float* queries = (const float*)d_in[2];
    float*       out     = (float*)d_out;

    // pick the largest power-of-two P (blocks per b) the workspace allows
    int P = 32;
    while (P > 1) {
        size_t need = (size_t)BB * P * NQ * WW * sizeof(float)
                    + (size_t)BB * P * NQ * 2 * sizeof(float);
        if (need <= ws_size) break;
        P >>= 1;
    }

    float* Opart  = (float*)d_ws;
    float* MSpart = Opart + (size_t)BB * P * NQ * WW;

    pool_main<<<dim3(BB * P), dim3(256), 0, stream>>>(h, mask, queries,
                                                      Opart, MSpart, P);
    pool_combine<<<dim3(BB * NQ), dim3(256), 0, stream>>>(Opart, MSpart, out, P);
}